// Round 11
// baseline (388.325 us; speedup 1.0000x reference)
//
#include <hip/hip_runtime.h>

// WindowAttention: B=8, C=128, H=W=256, ws=8, heads=4, d=32, n=64 tokens/window
// r11: 2048 blocks x 4 windows each (256 thr = 4 waves; wave h = head h).
// Compute body identical to r8 (pure-register attention via x16 MFMA whose
// k-mapping matches the x32 C/D layout; swapped-operand projections).
// NEW: software-pipelined window loop (T14 issue-early/write-late):
//   [B1 B2 C](w) -> Ot -> bar#1 -> issue x-loads(w+1) -> D E(w)
//   -> cvt+ds_write Xt[nxt] -> bar#2
// Phase-A HBM latency hides under D+E; prologue amortized 4x. The 4 windows
// are wx-consecutive in one batch -> same-XCD L2 locality for x lines.
// LDS 48K: Xt0[0,16K) Xt1[16K,32K) (swz (tok&15)<<4), Ot[32K,48K). 2 bars/window.
// __launch_bounds__(256,2): spill-free allocation regime (r0/r3/r5/r7/r8).

#define HH    256
#define WWID  256
#define SCALE 0.17677669529663687f
#define LOG2E 1.44269504088896340736f

typedef float  f32x4  __attribute__((ext_vector_type(4)));
typedef __bf16 bf16x8 __attribute__((ext_vector_type(8)));
typedef __bf16 bf16x4 __attribute__((ext_vector_type(4)));
typedef __bf16 bf16x2 __attribute__((ext_vector_type(2)));
typedef short  s16x4  __attribute__((ext_vector_type(4)));

#define OT_BASE 32768

__device__ __forceinline__ s16x4 pack4(f32x4 v) {
  bf16x4 b = {(__bf16)v[0], (__bf16)v[1], (__bf16)v[2], (__bf16)v[3]};
  return __builtin_bit_cast(s16x4, b);
}

#if __has_builtin(__builtin_amdgcn_mfma_f32_16x16x16bf16_1k)
__device__ __forceinline__ f32x4 mfma16(s16x4 a, s16x4 b, f32x4 c) {
  return __builtin_amdgcn_mfma_f32_16x16x16bf16_1k(a, b, c, 0, 0, 0);
}
#else
__device__ __forceinline__ f32x4 mfma16(s16x4 a, s16x4 b, f32x4 c) {
  asm("v_mfma_f32_16x16x16_bf16 %0, %1, %2, %0" : "+v"(c) : "v"(a), "v"(b));
  return c;
}
#endif

__global__ void prep_weights(const float* __restrict__ wqkv,
                             const float* __restrict__ wproj,
                             __bf16* __restrict__ wbf) {
  int i = blockIdx.x * 256 + threadIdx.x;          // 65536 total
  float v = (i < 49152) ? wqkv[i] : wproj[i - 49152];
  if (i < 16384) v *= SCALE * LOG2E;               // fold softmax scale + log2e into Wq
  wbf[i] = (__bf16)v;
}

__global__ __launch_bounds__(256, 2)
void winattn_main(const float* __restrict__ x,
                  const __bf16* __restrict__ wqkv,   // [384][128] bf16 (Q rows pre-scaled)
                  const __bf16* __restrict__ wproj,  // [128][128] bf16
                  const float* __restrict__ bproj,
                  float* __restrict__ out) {
  __shared__ __align__(16) char smem[49152];

  const int tid  = threadIdx.x;
  const int lane = tid & 63;
  const int wv   = tid >> 6;       // wave id == head id
  const int l15  = lane & 15;
  const int l4   = lane >> 4;

  // 2048 blocks: XCD k (bid&7) owns batch k; grp = bid>>3 covers 4 consecutive
  // windows (wx-major) -> adjacent 64B x/out lines on the same XCD.
  const int bid = blockIdx.x;
  const int b   = bid & 7;
  const int grp = bid >> 3;        // 0..255; windows grp*4 .. grp*4+3

  // Phase-A load task decode (constant per thread): 1024 tasks =
  // (cpair 64) x (ty 8) x (tx4 2); thread does it=0..3.
  int tcpair[4], tty[4], ttx4[4];
  #pragma unroll
  for (int it = 0; it < 4; ++it) {
    int idx = tid + it * 256;
    tcpair[it] = idx >> 4;
    int r = idx & 15;
    tty[it] = r >> 1;
    ttx4[it] = r & 1;
  }

  #define ISSUE_LOADS(widx, pv0, pv1)                                              \
    {                                                                              \
      int gy0_ = ((widx) >> 5) * 8, gx0_ = ((widx) & 31) * 8;                      \
      _Pragma("unroll")                                                            \
      for (int it = 0; it < 4; ++it) {                                             \
        const float* px = x + (((size_t)(b * 128 + 2 * tcpair[it]) * HH + gy0_ +   \
                                tty[it]) * WWID + gx0_ + ttx4[it] * 4);            \
        pv0[it] = *(const float4*)px;                                              \
        pv1[it] = *(const float4*)(px + (size_t)HH * WWID);                        \
      }                                                                            \
    }

  #define STORE_TILE(pv0, pv1, base)                                               \
    {                                                                              \
      _Pragma("unroll")                                                            \
      for (int it = 0; it < 4; ++it) {                                             \
        float a0_[4] = {pv0[it].x, pv0[it].y, pv0[it].z, pv0[it].w};               \
        float a1_[4] = {pv1[it].x, pv1[it].y, pv1[it].z, pv1[it].w};               \
        _Pragma("unroll")                                                          \
        for (int i = 0; i < 4; ++i) {                                              \
          int tok = tty[it] * 8 + ttx4[it] * 4 + i;                                \
          bf16x2 w2 = {(__bf16)a0_[i], (__bf16)a1_[i]};                            \
          int byte = (base) + ((tok * 256 + tcpair[it] * 4) ^ ((tok & 15) << 4));  \
          *(bf16x2*)(smem + byte) = w2;                                            \
        }                                                                          \
      }                                                                            \
    }

  // Xt fragment from buffer base; A/B operand lane mappings identical.
  #define XT_AFRAG(base, mt, kt) \
    (*(const bf16x8*)(smem + (base) + ((((mt) * 16 + l15) * 256 + ((kt) * 32 + l4 * 8) * 2) ^ \
                              ((((mt) * 16 + l15) & 15) << 4))))
  #define OT_AFRAG(mt, kt) \
    (*(const bf16x8*)(smem + OT_BASE + ((((mt) * 16 + l15) * 256 + ((kt) * 32 + l4 * 8) * 2) ^ \
                              ((((mt) * 16 + l15) & 15) << 4))))

  // -------- prologue: stage window 0 into Xt0 --------
  {
    float4 pv0[4], pv1[4];
    ISSUE_LOADS(grp * 4, pv0, pv1);
    STORE_TILE(pv0, pv1, 0);
  }
  __syncthreads();

  #pragma unroll
  for (int w = 0; w < 4; ++w) {
    const int XB = (w & 1) ? 16384 : 0;       // current Xt buffer
    const int NB = XB ^ 16384;                // next Xt buffer
    const int widx = grp * 4 + w;
    const int gy0 = (widx >> 5) * 8, gx0 = (widx & 31) * 8;

    // ---------------- B1: Q & K fused, SWAPPED -> registers ----------------
    s16x4 qb[2][4], kb[2][4];
    {
      f32x4 accQ[2][4] = {}, accK[2][4] = {};
      #pragma unroll
      for (int kt = 0; kt < 4; ++kt) {
        bf16x8 xf[4];
        #pragma unroll
        for (int mt = 0; mt < 4; ++mt) xf[mt] = XT_AFRAG(XB, mt, kt);
        #pragma unroll
        for (int nt2 = 0; nt2 < 2; ++nt2) {
          bf16x8 wq = *(const bf16x8*)(wqkv + (size_t)(wv * 32 + nt2 * 16 + l15) * 128 + kt * 32 + l4 * 8);
          bf16x8 wk = *(const bf16x8*)(wqkv + (size_t)(128 + wv * 32 + nt2 * 16 + l15) * 128 + kt * 32 + l4 * 8);
          #pragma unroll
          for (int mt = 0; mt < 4; ++mt) {
            accQ[nt2][mt] = __builtin_amdgcn_mfma_f32_16x16x32_bf16(wq, xf[mt], accQ[nt2][mt], 0, 0, 0);
            accK[nt2][mt] = __builtin_amdgcn_mfma_f32_16x16x32_bf16(wk, xf[mt], accK[nt2][mt], 0, 0, 0);
          }
        }
      }
      #pragma unroll
      for (int nt2 = 0; nt2 < 2; ++nt2)
        #pragma unroll
        for (int mt = 0; mt < 4; ++mt) {
          qb[nt2][mt] = pack4(accQ[nt2][mt]);
          kb[nt2][mt] = pack4(accK[nt2][mt]);
        }
    }

    // ---------------- B2: V non-swapped -> registers ----------------
    s16x4 vb[2][4];
    {
      f32x4 accV[2][4] = {};
      #pragma unroll
      for (int kt = 0; kt < 4; ++kt) {
        bf16x8 xf[4];
        #pragma unroll
        for (int mt = 0; mt < 4; ++mt) xf[mt] = XT_AFRAG(XB, mt, kt);
        #pragma unroll
        for (int nt2 = 0; nt2 < 2; ++nt2) {
          bf16x8 wf = *(const bf16x8*)(wqkv + (size_t)(256 + wv * 32 + nt2 * 16 + l15) * 128 + kt * 32 + l4 * 8);
          #pragma unroll
          for (int mt = 0; mt < 4; ++mt)
            accV[nt2][mt] = __builtin_amdgcn_mfma_f32_16x16x32_bf16(xf[mt], wf, accV[nt2][mt], 0, 0, 0);
        }
      }
      #pragma unroll
      for (int nt2 = 0; nt2 < 2; ++nt2)
        #pragma unroll
        for (int mt = 0; mt < 4; ++mt) vb[nt2][mt] = pack4(accV[nt2][mt]);
    }

    // ---------------- C: attention, pure registers ----------------
    #pragma unroll
    for (int t = 0; t < 4; ++t) {
      f32x4 st[4];
      #pragma unroll
      for (int m = 0; m < 4; ++m) {
        f32x4 z = {0.f, 0.f, 0.f, 0.f};
        st[m] = mfma16(kb[0][m], qb[0][t], z);
        st[m] = mfma16(kb[1][m], qb[1][t], st[m]);
      }
      float mx = st[0][0];
      #pragma unroll
      for (int m = 0; m < 4; ++m)
        #pragma unroll
        for (int r = 0; r < 4; ++r) mx = fmaxf(mx, st[m][r]);
      mx = fmaxf(mx, __shfl_xor(mx, 16));
      mx = fmaxf(mx, __shfl_xor(mx, 32));
      float p[4][4];
      float sm = 0.f;
      #pragma unroll
      for (int m = 0; m < 4; ++m)
        #pragma unroll
        for (int r = 0; r < 4; ++r) {
          p[m][r] = __builtin_amdgcn_exp2f(st[m][r] - mx);
          sm += p[m][r];
        }
      sm += __shfl_xor(sm, 16);
      sm += __shfl_xor(sm, 32);
      float inv = __builtin_amdgcn_rcpf(sm);
      s16x4 ap[4];
      #pragma unroll
      for (int m = 0; m < 4; ++m) {
        f32x4 pn = {p[m][0] * inv, p[m][1] * inv, p[m][2] * inv, p[m][3] * inv};
        ap[m] = pack4(pn);
      }
      f32x4 o0 = {0.f, 0.f, 0.f, 0.f}, o1 = {0.f, 0.f, 0.f, 0.f};
      #pragma unroll
      for (int m = 0; m < 4; ++m) {
        o0 = mfma16(ap[m], vb[0][m], o0);
        o1 = mfma16(ap[m], vb[1][m], o1);
      }
      // lane l15 = d, reg r = q; write Ot[64 tok][128 c]
      #pragma unroll
      for (int r = 0; r < 4; ++r) {
        int tok = t * 16 + l4 * 4 + r;
        int c0  = wv * 32 + l15;
        int sw  = (tok & 15) << 4;
        *(__bf16*)(smem + OT_BASE + ((tok * 256 + c0 * 2) ^ sw))        = (__bf16)o0[r];
        *(__bf16*)(smem + OT_BASE + ((tok * 256 + (c0 + 16) * 2) ^ sw)) = (__bf16)o1[r];
      }
    }
    __syncthreads();   // bar#1: Ot complete (D reads all heads' columns)

    // ---------------- prefetch next window's x (issue-early) ----------------
    float4 pv0[4], pv1[4];
    if (w < 3) ISSUE_LOADS(widx + 1, pv0, pv1);

    // ---------------- D: proj GEMM ----------------
    f32x4 pacc[2][4] = {};  // [o-tile][tok-tile]
    #pragma unroll
    for (int kt = 0; kt < 4; ++kt) {
      bf16x8 of[4];
      #pragma unroll
      for (int mt = 0; mt < 4; ++mt) of[mt] = OT_AFRAG(mt, kt);
      #pragma unroll
      for (int i = 0; i < 2; ++i) {
        bf16x8 wp = *(const bf16x8*)(wproj + (size_t)((wv * 2 + i) * 16 + l15) * 128 + kt * 32 + l4 * 8);
        #pragma unroll
        for (int mt = 0; mt < 4; ++mt)
          pacc[i][mt] = __builtin_amdgcn_mfma_f32_16x16x32_bf16(of[mt], wp, pacc[i][mt], 0, 0, 0);
      }
    }

    // ---------------- E: direct float4 writeout + bias ----------------
    #pragma unroll
    for (int i = 0; i < 2; ++i) {
      int o = (wv * 2 + i) * 16 + l15;
      float bias = bproj[o];
      float* obase = out + (size_t)(b * 128 + o) * ((size_t)HH * WWID) + gy0 * WWID + gx0;
      #pragma unroll
      for (int mt = 0; mt < 4; ++mt) {
        int tok0 = mt * 16 + l4 * 4;
        int ty = tok0 >> 3, tx0 = tok0 & 7;
        float4 f = {pacc[i][mt][0] + bias, pacc[i][mt][1] + bias,
                    pacc[i][mt][2] + bias, pacc[i][mt][3] + bias};
        *(float4*)(obase + ty * WWID + tx0) = f;
      }
    }

    // ---------------- write-late: stage next window into the spare buffer ----------------
    if (w < 3) {
      STORE_TILE(pv0, pv1, NB);
      __syncthreads();   // bar#2: Xt[nxt] ready; Ot free for next window
    }
  }
}

extern "C" void kernel_launch(void* const* d_in, const int* in_sizes, int n_in,
                              void* d_out, int out_size, void* d_ws, size_t ws_size,
                              hipStream_t stream) {
  const float* x     = (const float*)d_in[0];
  const float* wqkv  = (const float*)d_in[1];
  const float* wproj = (const float*)d_in[2];
  const float* bproj = (const float*)d_in[3];
  float* out = (float*)d_out;

  __bf16* wbf = (__bf16*)d_ws;   // 65536 bf16 = 128 KiB scratch
  prep_weights<<<256, 256, 0, stream>>>(wqkv, wproj, wbf);
  winattn_main<<<2048, 256, 0, stream>>>(x, wbf, wbf + 49152, bproj, out);
}

// Round 12
// 250.432 us; speedup vs baseline: 1.5506x; 1.5506x over previous
//
#include <hip/hip_runtime.h>

// WindowAttention: B=8, C=128, H=W=256, ws=8, heads=4, d=32, n=64 tokens/window
// One block = one window (8192 blocks, 256 thr = 4 waves). Wave h owns head h.
// r12 = r9 split-pass order + CROSS-PASS WEIGHT PREFETCH: each pass's weight
// fragments are issued one pass earlier (Q-wts under phase A; K-wts under Q;
// V-wts under K+softmax; proj-wts under V+PV). Exposed L2 latency ~0; prefetch
// regs consumed next pass (never held across two phases - r11's mistake).
// Projections/proj: v_mfma_f32_16x16x32_bf16 (swapped-operand trick); attention:
// v_mfma_f32_16x16x16_bf16 (k-mapping == x32 C/D layout -> Q/K/V/P in registers).
// LDS 32K: [0,16K) Xt[64][128]bf16 swz(tok&15)<<4; [16K,32K) Ot. 2 barriers.
// __launch_bounds__(256,2): spill-free allocation regime (r0/r3/r5/r8/r9).

#define HH    256
#define WWID  256
#define SCALE 0.17677669529663687f
#define LOG2E 1.44269504088896340736f

typedef float  f32x4  __attribute__((ext_vector_type(4)));
typedef __bf16 bf16x8 __attribute__((ext_vector_type(8)));
typedef __bf16 bf16x4 __attribute__((ext_vector_type(4)));
typedef __bf16 bf16x2 __attribute__((ext_vector_type(2)));
typedef short  s16x4  __attribute__((ext_vector_type(4)));

#define OT_BASE 16384

__device__ __forceinline__ s16x4 pack4(f32x4 v) {
  bf16x4 b = {(__bf16)v[0], (__bf16)v[1], (__bf16)v[2], (__bf16)v[3]};
  return __builtin_bit_cast(s16x4, b);
}

#if __has_builtin(__builtin_amdgcn_mfma_f32_16x16x16bf16_1k)
__device__ __forceinline__ f32x4 mfma16(s16x4 a, s16x4 b, f32x4 c) {
  return __builtin_amdgcn_mfma_f32_16x16x16bf16_1k(a, b, c, 0, 0, 0);
}
#else
__device__ __forceinline__ f32x4 mfma16(s16x4 a, s16x4 b, f32x4 c) {
  asm("v_mfma_f32_16x16x16_bf16 %0, %1, %2, %0" : "+v"(c) : "v"(a), "v"(b));
  return c;
}
#endif

__global__ void prep_weights(const float* __restrict__ wqkv,
                             const float* __restrict__ wproj,
                             __bf16* __restrict__ wbf) {
  int i = blockIdx.x * 256 + threadIdx.x;          // 65536 total
  float v = (i < 49152) ? wqkv[i] : wproj[i - 49152];
  if (i < 16384) v *= SCALE * LOG2E;               // fold softmax scale + log2e into Wq
  wbf[i] = (__bf16)v;
}

__global__ __launch_bounds__(256, 2)
void winattn_main(const float* __restrict__ x,
                  const __bf16* __restrict__ wqkv,   // [384][128] bf16 (Q rows pre-scaled)
                  const __bf16* __restrict__ wproj,  // [128][128] bf16
                  const float* __restrict__ bproj,
                  float* __restrict__ out) {
  __shared__ __align__(16) char smem[32768];

  const int tid  = threadIdx.x;
  const int lane = tid & 63;
  const int wv   = tid >> 6;       // wave id == head id
  const int l15  = lane & 15;
  const int l4   = lane >> 4;

  // XCD-aware swizzle: XCD k owns batch k.
  const int bid = blockIdx.x;
  const int win = ((bid & 7) << 10) | (bid >> 3);
  const int b   = win >> 10;
  const int wy  = (win >> 5) & 31;
  const int wx  = win & 31;
  const int gy0 = wy * 8, gx0 = wx * 8;

  // weight-fragment address helper: row block base + per-lane offset
  #define WROW(rowbase) ((size_t)((rowbase) + l15) * 128 + l4 * 8)

  // ---- prefetch Q-weights (consumed in Q pass; in flight under phase A) ----
  bf16x8 wqf[2][4];
  #pragma unroll
  for (int nt2 = 0; nt2 < 2; ++nt2)
    #pragma unroll
    for (int kt = 0; kt < 4; ++kt)
      wqf[nt2][kt] = *(const bf16x8*)(wqkv + WROW(wv * 32 + nt2 * 16) + kt * 32);

  // ---------------- Phase A: load window -> Xt[tok][c] bf16 (swz &15) ----------------
  #pragma unroll
  for (int it = 0; it < 4; ++it) {
    int idx   = tid + it * 256;        // 1024 tasks: (cpair 64) x (ty 8) x (tx4 2)
    int cpair = idx >> 4;
    int r     = idx & 15;
    int ty    = r >> 1, tx4 = r & 1;
    const float* px = x + (((size_t)(b * 128 + 2 * cpair) * HH + gy0 + ty) * WWID + gx0 + tx4 * 4);
    float4 v0 = *(const float4*)px;
    float4 v1 = *(const float4*)(px + (size_t)HH * WWID);
    float a0[4] = {v0.x, v0.y, v0.z, v0.w};
    float a1[4] = {v1.x, v1.y, v1.z, v1.w};
    #pragma unroll
    for (int i = 0; i < 4; ++i) {
      int tok = ty * 8 + tx4 * 4 + i;
      bf16x2 w2 = {(__bf16)a0[i], (__bf16)a1[i]};
      int byte = (tok * 256 + cpair * 4) ^ ((tok & 15) << 4);
      *(bf16x2*)(smem + byte) = w2;
    }
  }
  __syncthreads();

  // Xt fragment; A- and B-operand lane mappings are identical.
  #define XT_AFRAG(mt, kt) \
    (*(const bf16x8*)(smem + ((((mt) * 16 + l15) * 256 + ((kt) * 32 + l4 * 8) * 2) ^ \
                              ((((mt) * 16 + l15) & 15) << 4))))
  #define OT_AFRAG(mt, kt) \
    (*(const bf16x8*)(smem + OT_BASE + ((((mt) * 16 + l15) * 256 + ((kt) * 32 + l4 * 8) * 2) ^ \
                              ((((mt) * 16 + l15) & 15) << 4))))

  // ---------------- Q pass (swapped: lane=tok, regs=d); prefetch K-wts ----------------
  bf16x8 wkf[2][4];
  #pragma unroll
  for (int nt2 = 0; nt2 < 2; ++nt2)
    #pragma unroll
    for (int kt = 0; kt < 4; ++kt)
      wkf[nt2][kt] = *(const bf16x8*)(wqkv + WROW(128 + wv * 32 + nt2 * 16) + kt * 32);

  s16x4 qb[2][4];
  {
    f32x4 acc[2][4] = {};
    #pragma unroll
    for (int kt = 0; kt < 4; ++kt) {
      bf16x8 xf[4];
      #pragma unroll
      for (int mt = 0; mt < 4; ++mt) xf[mt] = XT_AFRAG(mt, kt);
      #pragma unroll
      for (int nt2 = 0; nt2 < 2; ++nt2)
        #pragma unroll
        for (int mt = 0; mt < 4; ++mt)
          acc[nt2][mt] = __builtin_amdgcn_mfma_f32_16x16x32_bf16(wqf[nt2][kt], xf[mt], acc[nt2][mt], 0, 0, 0);
    }
    #pragma unroll
    for (int nt2 = 0; nt2 < 2; ++nt2)
      #pragma unroll
      for (int mt = 0; mt < 4; ++mt) qb[nt2][mt] = pack4(acc[nt2][mt]);
  }

  // ---------------- K pass (swapped); prefetch V-wts ----------------
  bf16x8 wvf[2][4];
  #pragma unroll
  for (int nt2 = 0; nt2 < 2; ++nt2)
    #pragma unroll
    for (int kt = 0; kt < 4; ++kt)
      wvf[nt2][kt] = *(const bf16x8*)(wqkv + WROW(256 + wv * 32 + nt2 * 16) + kt * 32);

  s16x4 kb[2][4];
  {
    f32x4 acc[2][4] = {};
    #pragma unroll
    for (int kt = 0; kt < 4; ++kt) {
      bf16x8 xf[4];
      #pragma unroll
      for (int mt = 0; mt < 4; ++mt) xf[mt] = XT_AFRAG(mt, kt);
      #pragma unroll
      for (int nt2 = 0; nt2 < 2; ++nt2)
        #pragma unroll
        for (int mt = 0; mt < 4; ++mt)
          acc[nt2][mt] = __builtin_amdgcn_mfma_f32_16x16x32_bf16(wkf[nt2][kt], xf[mt], acc[nt2][mt], 0, 0, 0);
    }
    #pragma unroll
    for (int nt2 = 0; nt2 < 2; ++nt2)
      #pragma unroll
      for (int mt = 0; mt < 4; ++mt) kb[nt2][mt] = pack4(acc[nt2][mt]);
  }

  // ---------------- C1: S^T + softmax -> packed P (frees Q,K) ----------------
  s16x4 ap[4][4];   // [q-tile t][key-tile m]
  #pragma unroll
  for (int t = 0; t < 4; ++t) {
    f32x4 st[4];
    #pragma unroll
    for (int m = 0; m < 4; ++m) {
      f32x4 z = {0.f, 0.f, 0.f, 0.f};
      st[m] = mfma16(kb[0][m], qb[0][t], z);
      st[m] = mfma16(kb[1][m], qb[1][t], st[m]);
    }
    float mx = st[0][0];
    #pragma unroll
    for (int m = 0; m < 4; ++m)
      #pragma unroll
      for (int r = 0; r < 4; ++r) mx = fmaxf(mx, st[m][r]);
    mx = fmaxf(mx, __shfl_xor(mx, 16));
    mx = fmaxf(mx, __shfl_xor(mx, 32));
    float p[4][4];
    float sm = 0.f;
    #pragma unroll
    for (int m = 0; m < 4; ++m)
      #pragma unroll
      for (int r = 0; r < 4; ++r) {
        p[m][r] = __builtin_amdgcn_exp2f(st[m][r] - mx);
        sm += p[m][r];
      }
    sm += __shfl_xor(sm, 16);
    sm += __shfl_xor(sm, 32);
    float inv = __builtin_amdgcn_rcpf(sm);
    #pragma unroll
    for (int m = 0; m < 4; ++m) {
      f32x4 pn = {p[m][0] * inv, p[m][1] * inv, p[m][2] * inv, p[m][3] * inv};
      ap[t][m] = pack4(pn);
    }
  }

  // ---------------- V pass (non-swapped: lane=d, regs=tok); prefetch proj-wts ----------------
  bf16x8 wpf[2][4];
  #pragma unroll
  for (int i = 0; i < 2; ++i)
    #pragma unroll
    for (int kt = 0; kt < 4; ++kt)
      wpf[i][kt] = *(const bf16x8*)(wproj + WROW((wv * 2 + i) * 16) + kt * 32);

  s16x4 vb[2][4];
  {
    f32x4 acc[2][4] = {};
    #pragma unroll
    for (int kt = 0; kt < 4; ++kt) {
      bf16x8 xf[4];
      #pragma unroll
      for (int mt = 0; mt < 4; ++mt) xf[mt] = XT_AFRAG(mt, kt);
      #pragma unroll
      for (int nt2 = 0; nt2 < 2; ++nt2)
        #pragma unroll
        for (int mt = 0; mt < 4; ++mt)
          acc[nt2][mt] = __builtin_amdgcn_mfma_f32_16x16x32_bf16(xf[mt], wvf[nt2][kt], acc[nt2][mt], 0, 0, 0);
    }
    #pragma unroll
    for (int nt2 = 0; nt2 < 2; ++nt2)
      #pragma unroll
      for (int mt = 0; mt < 4; ++mt) vb[nt2][mt] = pack4(acc[nt2][mt]);
  }

  // ---------------- C2: PV per q-tile, write Ot immediately ----------------
  #pragma unroll
  for (int t = 0; t < 4; ++t) {
    f32x4 o0 = {0.f, 0.f, 0.f, 0.f}, o1 = {0.f, 0.f, 0.f, 0.f};
    #pragma unroll
    for (int m = 0; m < 4; ++m) {
      o0 = mfma16(ap[t][m], vb[0][m], o0);
      o1 = mfma16(ap[t][m], vb[1][m], o1);
    }
    // lane l15 = d, reg r = q (t*16 + l4*4 + r); write Ot[64 tok][128 c]
    #pragma unroll
    for (int r = 0; r < 4; ++r) {
      int tok = t * 16 + l4 * 4 + r;
      int c0  = wv * 32 + l15;
      int sw  = (tok & 15) << 4;
      *(__bf16*)(smem + OT_BASE + ((tok * 256 + c0 * 2) ^ sw))        = (__bf16)o0[r];
      *(__bf16*)(smem + OT_BASE + ((tok * 256 + (c0 + 16) * 2) ^ sw)) = (__bf16)o1[r];
    }
  }
  __syncthreads();   // Ot complete -> D may read all heads' columns

  // ---------------- Phase D: proj GEMM (weights prefetched) ----------------
  f32x4 pacc[2][4] = {};  // [o-tile][tok-tile]
  #pragma unroll
  for (int kt = 0; kt < 4; ++kt) {
    bf16x8 of[4];
    #pragma unroll
    for (int mt = 0; mt < 4; ++mt) of[mt] = OT_AFRAG(mt, kt);
    #pragma unroll
    for (int i = 0; i < 2; ++i)
      #pragma unroll
      for (int mt = 0; mt < 4; ++mt)
        pacc[i][mt] = __builtin_amdgcn_mfma_f32_16x16x32_bf16(of[mt], wpf[i][kt], pacc[i][mt], 0, 0, 0);
  }

  // ---------------- Phase E: direct float4 writeout + bias ----------------
  #pragma unroll
  for (int i = 0; i < 2; ++i) {
    int o = (wv * 2 + i) * 16 + l15;
    float bias = bproj[o];
    float* obase = out + (size_t)(b * 128 + o) * ((size_t)HH * WWID) + gy0 * WWID + gx0;
    #pragma unroll
    for (int mt = 0; mt < 4; ++mt) {
      int tok0 = mt * 16 + l4 * 4;            // 4 consecutive toks within one y-row
      int ty = tok0 >> 3, tx0 = tok0 & 7;
      float4 f = {pacc[i][mt][0] + bias, pacc[i][mt][1] + bias,
                  pacc[i][mt][2] + bias, pacc[i][mt][3] + bias};
      *(float4*)(obase + ty * WWID + tx0) = f;
    }
  }
}

extern "C" void kernel_launch(void* const* d_in, const int* in_sizes, int n_in,
                              void* d_out, int out_size, void* d_ws, size_t ws_size,
                              hipStream_t stream) {
  const float* x     = (const float*)d_in[0];
  const float* wqkv  = (const float*)d_in[1];
  const float* wproj = (const float*)d_in[2];
  const float* bproj = (const float*)d_in[3];
  float* out = (float*)d_out;

  __bf16* wbf = (__bf16*)d_ws;   // 65536 bf16 = 128 KiB scratch
  prep_weights<<<256, 256, 0, stream>>>(wqkv, wproj, wbf);
  winattn_main<<<8192, 256, 0, stream>>>(x, wbf, wbf + 49152, bproj, out);
}

// Round 13
// 249.381 us; speedup vs baseline: 1.5572x; 1.0042x over previous
//
#include <hip/hip_runtime.h>

// WindowAttention: B=8, C=128, H=W=256, ws=8, heads=4, d=32, n=64 tokens/window
// One block = one window (8192 blocks, 256 thr = 4 waves). Wave h owns head h.
// r13 = r12 skeleton + three proven micro-wins:
//  (1) Q+K fused kt-loop (r8-proven; -16 ds_read_b128/wave), in-loop weight loads
//  (2) PV computed as mfma16(vb, ap) -> D(lane=tok, regs=d) -> Ot stored as 8
//      packed ds_write_b64 per wave (was 32 scalar b16)
//  (3) s_setprio(1) around MFMA clusters (T5; present in best-timed r5/r6)
// Projections/proj: v_mfma_f32_16x16x32_bf16 (swapped-operand trick); attention:
// v_mfma_f32_16x16x16_bf16 (k-mapping == x32 C/D layout -> Q/K/V/P in registers).
// LDS 32K: [0,16K) Xt[64][128]bf16 swz(tok&15)<<4; [16K,32K) Ot. 2 barriers.
// __launch_bounds__(256,2): spill-free allocation regime (r0/r3/r5/r8/r9/r12).

#define HH    256
#define WWID  256
#define SCALE 0.17677669529663687f
#define LOG2E 1.44269504088896340736f

typedef float  f32x4  __attribute__((ext_vector_type(4)));
typedef __bf16 bf16x8 __attribute__((ext_vector_type(8)));
typedef __bf16 bf16x4 __attribute__((ext_vector_type(4)));
typedef __bf16 bf16x2 __attribute__((ext_vector_type(2)));
typedef short  s16x4  __attribute__((ext_vector_type(4)));

#define OT_BASE 16384

__device__ __forceinline__ s16x4 pack4(f32x4 v) {
  bf16x4 b = {(__bf16)v[0], (__bf16)v[1], (__bf16)v[2], (__bf16)v[3]};
  return __builtin_bit_cast(s16x4, b);
}

#if __has_builtin(__builtin_amdgcn_mfma_f32_16x16x16bf16_1k)
__device__ __forceinline__ f32x4 mfma16(s16x4 a, s16x4 b, f32x4 c) {
  return __builtin_amdgcn_mfma_f32_16x16x16bf16_1k(a, b, c, 0, 0, 0);
}
#else
__device__ __forceinline__ f32x4 mfma16(s16x4 a, s16x4 b, f32x4 c) {
  asm("v_mfma_f32_16x16x16_bf16 %0, %1, %2, %0" : "+v"(c) : "v"(a), "v"(b));
  return c;
}
#endif

__global__ void prep_weights(const float* __restrict__ wqkv,
                             const float* __restrict__ wproj,
                             __bf16* __restrict__ wbf) {
  int i = blockIdx.x * 256 + threadIdx.x;          // 65536 total
  float v = (i < 49152) ? wqkv[i] : wproj[i - 49152];
  if (i < 16384) v *= SCALE * LOG2E;               // fold softmax scale + log2e into Wq
  wbf[i] = (__bf16)v;
}

__global__ __launch_bounds__(256, 2)
void winattn_main(const float* __restrict__ x,
                  const __bf16* __restrict__ wqkv,   // [384][128] bf16 (Q rows pre-scaled)
                  const __bf16* __restrict__ wproj,  // [128][128] bf16
                  const float* __restrict__ bproj,
                  float* __restrict__ out) {
  __shared__ __align__(16) char smem[32768];

  const int tid  = threadIdx.x;
  const int lane = tid & 63;
  const int wv   = tid >> 6;       // wave id == head id
  const int l15  = lane & 15;
  const int l4   = lane >> 4;

  // XCD-aware swizzle: XCD k owns batch k.
  const int bid = blockIdx.x;
  const int win = ((bid & 7) << 10) | (bid >> 3);
  const int b   = win >> 10;
  const int wy  = (win >> 5) & 31;
  const int wx  = win & 31;
  const int gy0 = wy * 8, gx0 = wx * 8;

  // ---------------- Phase A: load window -> Xt[tok][c] bf16 (swz &15) ----------------
  #pragma unroll
  for (int it = 0; it < 4; ++it) {
    int idx   = tid + it * 256;        // 1024 tasks: (cpair 64) x (ty 8) x (tx4 2)
    int cpair = idx >> 4;
    int r     = idx & 15;
    int ty    = r >> 1, tx4 = r & 1;
    const float* px = x + (((size_t)(b * 128 + 2 * cpair) * HH + gy0 + ty) * WWID + gx0 + tx4 * 4);
    float4 v0 = *(const float4*)px;
    float4 v1 = *(const float4*)(px + (size_t)HH * WWID);
    float a0[4] = {v0.x, v0.y, v0.z, v0.w};
    float a1[4] = {v1.x, v1.y, v1.z, v1.w};
    #pragma unroll
    for (int i = 0; i < 4; ++i) {
      int tok = ty * 8 + tx4 * 4 + i;
      bf16x2 w2 = {(__bf16)a0[i], (__bf16)a1[i]};
      int byte = (tok * 256 + cpair * 4) ^ ((tok & 15) << 4);
      *(bf16x2*)(smem + byte) = w2;
    }
  }
  __syncthreads();

  // Xt fragment; A- and B-operand lane mappings are identical.
  #define XT_AFRAG(mt, kt) \
    (*(const bf16x8*)(smem + ((((mt) * 16 + l15) * 256 + ((kt) * 32 + l4 * 8) * 2) ^ \
                              ((((mt) * 16 + l15) & 15) << 4))))
  #define OT_AFRAG(mt, kt) \
    (*(const bf16x8*)(smem + OT_BASE + ((((mt) * 16 + l15) * 256 + ((kt) * 32 + l4 * 8) * 2) ^ \
                              ((((mt) * 16 + l15) & 15) << 4))))

  // ---------------- B1: Q & K fused, SWAPPED (lane=tok, regs=d) ----------------
  s16x4 qb[2][4], kb[2][4];
  {
    f32x4 accQ[2][4] = {}, accK[2][4] = {};
    #pragma unroll
    for (int kt = 0; kt < 4; ++kt) {
      bf16x8 xf[4];
      #pragma unroll
      for (int mt = 0; mt < 4; ++mt) xf[mt] = XT_AFRAG(mt, kt);
      #pragma unroll
      for (int nt2 = 0; nt2 < 2; ++nt2) {
        bf16x8 wq = *(const bf16x8*)(wqkv + (size_t)(wv * 32 + nt2 * 16 + l15) * 128 + kt * 32 + l4 * 8);
        bf16x8 wk = *(const bf16x8*)(wqkv + (size_t)(128 + wv * 32 + nt2 * 16 + l15) * 128 + kt * 32 + l4 * 8);
        __builtin_amdgcn_s_setprio(1);
        #pragma unroll
        for (int mt = 0; mt < 4; ++mt) {
          accQ[nt2][mt] = __builtin_amdgcn_mfma_f32_16x16x32_bf16(wq, xf[mt], accQ[nt2][mt], 0, 0, 0);
          accK[nt2][mt] = __builtin_amdgcn_mfma_f32_16x16x32_bf16(wk, xf[mt], accK[nt2][mt], 0, 0, 0);
        }
        __builtin_amdgcn_s_setprio(0);
      }
    }
    #pragma unroll
    for (int nt2 = 0; nt2 < 2; ++nt2)
      #pragma unroll
      for (int mt = 0; mt < 4; ++mt) {
        qb[nt2][mt] = pack4(accQ[nt2][mt]);
        kb[nt2][mt] = pack4(accK[nt2][mt]);
      }
  }

  // ---------------- C1: S^T + softmax -> packed P (frees Q,K) ----------------
  s16x4 ap[4][4];   // [q-tile t][key-tile m]; lane=q, regs=key
  #pragma unroll
  for (int t = 0; t < 4; ++t) {
    f32x4 st[4];
    __builtin_amdgcn_s_setprio(1);
    #pragma unroll
    for (int m = 0; m < 4; ++m) {
      f32x4 z = {0.f, 0.f, 0.f, 0.f};
      st[m] = mfma16(kb[0][m], qb[0][t], z);
      st[m] = mfma16(kb[1][m], qb[1][t], st[m]);
    }
    __builtin_amdgcn_s_setprio(0);
    float mx = st[0][0];
    #pragma unroll
    for (int m = 0; m < 4; ++m)
      #pragma unroll
      for (int r = 0; r < 4; ++r) mx = fmaxf(mx, st[m][r]);
    mx = fmaxf(mx, __shfl_xor(mx, 16));
    mx = fmaxf(mx, __shfl_xor(mx, 32));
    float p[4][4];
    float sm = 0.f;
    #pragma unroll
    for (int m = 0; m < 4; ++m)
      #pragma unroll
      for (int r = 0; r < 4; ++r) {
        p[m][r] = __builtin_amdgcn_exp2f(st[m][r] - mx);
        sm += p[m][r];
      }
    sm += __shfl_xor(sm, 16);
    sm += __shfl_xor(sm, 32);
    float inv = __builtin_amdgcn_rcpf(sm);
    #pragma unroll
    for (int m = 0; m < 4; ++m) {
      f32x4 pn = {p[m][0] * inv, p[m][1] * inv, p[m][2] * inv, p[m][3] * inv};
      ap[t][m] = pack4(pn);
    }
  }

  // ---------------- V pass (non-swapped: lane=d, regs=tok) ----------------
  s16x4 vb[2][4];
  {
    f32x4 acc[2][4] = {};
    #pragma unroll
    for (int kt = 0; kt < 4; ++kt) {
      bf16x8 xf[4];
      #pragma unroll
      for (int mt = 0; mt < 4; ++mt) xf[mt] = XT_AFRAG(mt, kt);
      #pragma unroll
      for (int nt2 = 0; nt2 < 2; ++nt2) {
        bf16x8 w = *(const bf16x8*)(wqkv + (size_t)(256 + wv * 32 + nt2 * 16 + l15) * 128 + kt * 32 + l4 * 8);
        __builtin_amdgcn_s_setprio(1);
        #pragma unroll
        for (int mt = 0; mt < 4; ++mt)
          acc[nt2][mt] = __builtin_amdgcn_mfma_f32_16x16x32_bf16(xf[mt], w, acc[nt2][mt], 0, 0, 0);
        __builtin_amdgcn_s_setprio(0);
      }
    }
    #pragma unroll
    for (int nt2 = 0; nt2 < 2; ++nt2)
      #pragma unroll
      for (int mt = 0; mt < 4; ++mt) vb[nt2][mt] = pack4(acc[nt2][mt]);
  }

  // ---------------- C2: PV transposed (lane=tok, regs=d) + packed Ot stores ----------------
  #pragma unroll
  for (int t = 0; t < 4; ++t) {
    f32x4 o0 = {0.f, 0.f, 0.f, 0.f}, o1 = {0.f, 0.f, 0.f, 0.f};
    __builtin_amdgcn_s_setprio(1);
    #pragma unroll
    for (int m = 0; m < 4; ++m) {
      o0 = mfma16(vb[0][m], ap[t][m], o0);   // D(lane = ap-lane = q/tok, regs = vb-lane = d)
      o1 = mfma16(vb[1][m], ap[t][m], o1);
    }
    __builtin_amdgcn_s_setprio(0);
    int tok = t * 16 + l15;
    int sw  = (tok & 15) << 4;
    s16x4 p0 = pack4(o0), p1 = pack4(o1);
    int c0 = wv * 32 + l4 * 4;              // 4 consecutive d per reg-group
    *(s16x4*)(smem + OT_BASE + ((tok * 256 + c0 * 2) ^ sw))          = p0;
    *(s16x4*)(smem + OT_BASE + ((tok * 256 + (c0 + 16) * 2) ^ sw))   = p1;
  }
  __syncthreads();   // Ot complete -> D may read all heads' columns

  // ---------------- Phase D: proj GEMM ----------------
  f32x4 pacc[2][4] = {};  // [o-tile][tok-tile]
  #pragma unroll
  for (int kt = 0; kt < 4; ++kt) {
    bf16x8 of[4];
    #pragma unroll
    for (int mt = 0; mt < 4; ++mt) of[mt] = OT_AFRAG(mt, kt);
    #pragma unroll
    for (int i = 0; i < 2; ++i) {
      bf16x8 wp = *(const bf16x8*)(wproj + (size_t)((wv * 2 + i) * 16 + l15) * 128 + kt * 32 + l4 * 8);
      __builtin_amdgcn_s_setprio(1);
      #pragma unroll
      for (int mt = 0; mt < 4; ++mt)
        pacc[i][mt] = __builtin_amdgcn_mfma_f32_16x16x32_bf16(of[mt], wp, pacc[i][mt], 0, 0, 0);
      __builtin_amdgcn_s_setprio(0);
    }
  }

  // ---------------- Phase E: direct float4 writeout + bias ----------------
  #pragma unroll
  for (int i = 0; i < 2; ++i) {
    int o = (wv * 2 + i) * 16 + l15;
    float bias = bproj[o];
    float* obase = out + (size_t)(b * 128 + o) * ((size_t)HH * WWID) + gy0 * WWID + gx0;
    #pragma unroll
    for (int mt = 0; mt < 4; ++mt) {
      int tok0 = mt * 16 + l4 * 4;            // 4 consecutive toks within one y-row
      int ty = tok0 >> 3, tx0 = tok0 & 7;
      float4 f = {pacc[i][mt][0] + bias, pacc[i][mt][1] + bias,
                  pacc[i][mt][2] + bias, pacc[i][mt][3] + bias};
      *(float4*)(obase + ty * WWID + tx0) = f;
    }
  }
}

extern "C" void kernel_launch(void* const* d_in, const int* in_sizes, int n_in,
                              void* d_out, int out_size, void* d_ws, size_t ws_size,
                              hipStream_t stream) {
  const float* x     = (const float*)d_in[0];
  const float* wqkv  = (const float*)d_in[1];
  const float* wproj = (const float*)d_in[2];
  const float* bproj = (const float*)d_in[3];
  float* out = (float*)d_out;

  __bf16* wbf = (__bf16*)d_ws;   // 65536 bf16 = 128 KiB scratch
  prep_weights<<<256, 256, 0, stream>>>(wqkv, wproj, wbf);
  winattn_main<<<8192, 256, 0, stream>>>(x, wbf, wbf + 49152, bproj, out);
}